// Round 9
// baseline (248.363 us; speedup 1.0000x reference)
//
#include <hip/hip_runtime.h>
#include <hip/hip_bf16.h>

// GravNetConv: N=16384, C_IN=128, S=4, P=32, K=16, C_OUT=128.
// Mask-free path: [k1] proj (fp64 s) -> [k2t] threshold via radix-ladder histogram ->
// [memset cnt] -> [k2b_ext] full N^2 Gram-form scan, register mask words, local bit
// extract -> atomic append to per-query candidate lists (~150/query; 64MB mask
// round-trip eliminated) -> [k3_sel3] exact keys + kmax-anchored class histogram +
// rank -> winners -> coalesced aggregation -> [k4a/k4_out2] output GEMM.
// Fallback path (ws_size < 23.6MB): round-2 kernels.

#define NPTS 16384
#define CIN  128
#define SD   4
#define PD   32
#define KNN  16
#define COUT 128
#define FLTMAX 3.4028234663852886e+38f
#define NBIN 33
#define QPB  8      // k3 queries per block
#define QCAP 512    // per-query candidate cap
#define MCAP 128    // per-query qualifier cap (fallback scan if exceeded)

typedef float v2f __attribute__((ext_vector_type(2)));
typedef unsigned int uint;
typedef unsigned long long u64;

// ---- workspace layout ----
#define WS_S4     0            // N * float4 = 256 KB
#define WS_H      0x40000      // N * 32 f32 = 2 MB          (ends 0x240000)
#define WS_T2     0x240000     // N f32 = 64 KB
#define WS_CNT    0x250000     // N u32 = 64 KB
#define WS_WT     0x260000     // 192*128 f32 = 96 KB        (ends 0x278000)
#define WS_AGG    0x280000     // [N][64] f32 = 4 MB         (ends 0x680000)
#define WS_CAND   0x680000     // N * QCAP u16 = 16 MB       (ends 0x1680000)
#define WS_NEED   0x1680000    // 23.6 MB (< proven 24.1 MB)
// ---- fallback offsets ----
#define WS_CJ_F   0x400000
#define WS_AGG_F  0xC00000
#define WS_WT_F   0x1000000
#define JS   16
#define TJF  (NPTS/JS)

__device__ __forceinline__ float d2f(const float4 a, const float4 b) {
  v2f d0 = {a.x - b.x, a.y - b.y};
  v2f d1 = {a.z - b.z, a.w - b.w};
  v2f pr = d0*d0 + d1*d1;
  return pr.x + pr.y;
}

// ---------------- Kernel 1: s (fp64 accumulate) and h projections ----------------
__global__ __launch_bounds__(256) void k1_proj(
    const float* __restrict__ x, const float* __restrict__ Ws, const float* __restrict__ bs,
    const float* __restrict__ Wh, const float* __restrict__ bh,
    float4* __restrict__ s4, float* __restrict__ h) {
  __shared__ float  lw[36*128];
  __shared__ float  lx[64*132];
  __shared__ double rs[3*64*5];
  __shared__ float  rh[3*64*33];
  const int t = threadIdx.x;
  const int row0 = blockIdx.x * 64;
  for (int i2 = t; i2 < 36*128; i2 += 256)
    lw[i2] = (i2 < 512) ? Ws[i2] : Wh[i2 - 512];
#pragma unroll
  for (int g = 0; g < 8; ++g) {
    int fi = g*256 + t;
    int r = fi >> 5, c4 = fi & 31;
    *(float4*)&lx[r*132 + c4*4] = *(const float4*)&x[(size_t)(row0 + r)*CIN + c4*4];
  }
  __syncthreads();
  const int kq = t >> 6;
  const int r  = t & 63;
  const int kb = kq * 32;
  double sacc[4] = {0.0, 0.0, 0.0, 0.0};
  float  hacc[32];
#pragma unroll
  for (int p = 0; p < 32; ++p) hacc[p] = 0.f;
#pragma unroll
  for (int k4 = 0; k4 < 8; ++k4) {
    float4 xv = *(const float4*)&lx[r*132 + kb + k4*4];
    int kg = kb + k4*4;
#pragma unroll
    for (int p = 0; p < 4; ++p) {
      float4 wv = *(const float4*)&lw[p*128 + kg];
      sacc[p] = fma((double)xv.x, (double)wv.x, sacc[p]);
      sacc[p] = fma((double)xv.y, (double)wv.y, sacc[p]);
      sacc[p] = fma((double)xv.z, (double)wv.z, sacc[p]);
      sacc[p] = fma((double)xv.w, (double)wv.w, sacc[p]);
    }
#pragma unroll
    for (int p = 0; p < 32; ++p) {
      float4 wv = *(const float4*)&lw[(4+p)*128 + kg];
      hacc[p] = fmaf(xv.x, wv.x, fmaf(xv.y, wv.y, fmaf(xv.z, wv.z, fmaf(xv.w, wv.w, hacc[p]))));
    }
  }
  if (kq > 0) {
    const int bq = kq - 1;
#pragma unroll
    for (int d = 0; d < 4; ++d) rs[(bq*64 + r)*5 + d] = sacc[d];
#pragma unroll
    for (int p = 0; p < 32; ++p) rh[(bq*64 + r)*33 + p] = hacc[p];
  }
  __syncthreads();
  if (kq == 0) {
    const int row = row0 + r;
    float so[4];
#pragma unroll
    for (int d = 0; d < 4; ++d) {
      double sd = sacc[d] + rs[(0*64 + r)*5 + d] + rs[(1*64 + r)*5 + d]
                + rs[(2*64 + r)*5 + d] + (double)bs[d];
      so[d] = (float)sd;
    }
    s4[row] = make_float4(so[0], so[1], so[2], so[3]);
#pragma unroll
    for (int p4 = 0; p4 < 8; ++p4) {
      float o[4];
#pragma unroll
      for (int c = 0; c < 4; ++c) {
        int p = p4*4 + c;
        o[c] = hacc[p] + rh[(0*64 + r)*33 + p] + rh[(1*64 + r)*33 + p]
             + rh[(2*64 + r)*33 + p] + bh[p];
      }
      *(float4*)&h[(size_t)row*PD + p4*4] = make_float4(o[0], o[1], o[2], o[3]);
    }
  }
}

// ---------------- Kernel 2t: per-query threshold via radix-ladder histogram ----------------
__global__ __launch_bounds__(256) void k2t_thresh(
    const float4* __restrict__ s4, float* __restrict__ t2) {
  __shared__ float4 tile[2064];
  __shared__ uint   lhist[256*NBIN];
  const int t = threadIdx.x;
#pragma unroll
  for (int g = 0; g < 8; ++g) {
    int j = g*256 + t;
    tile[j + (j >> 7)] = s4[j];
  }
#pragma unroll
  for (int b = 0; b < NBIN; ++b) lhist[t*NBIN + b] = 0u;
  const int ql = t >> 4, tq = t & 15;
  const int q  = blockIdx.x*16 + ql;
  const float4 sq = s4[q];
  __syncthreads();
  float tau = d2f(sq, tile[tq*129]);
#pragma unroll
  for (int m = 1; m < 16; m <<= 1) tau = fmaxf(tau, __shfl_xor(tau, m, 16));
  const int ktop = (int)(__float_as_uint(tau) >> 21);
  const int hb = t*NBIN;
#pragma unroll 4
  for (int u = 0; u < 128; ++u) {
    float4 p = tile[tq*129 + u];
    float e = d2f(sq, p);
    int key = (int)(__float_as_uint(e) >> 21);
    int rel = ktop - key;
    rel = rel < 0 ? 0 : (rel > 32 ? 32 : rel);
    atomicAdd(&lhist[hb + rel], 1u);
  }
  __syncthreads();
  uint c0 = 0, c1 = 0;
  const int qb = ql*16;
  for (int u = 0; u < 16; ++u) {
    c0 += lhist[(qb + u)*NBIN + tq*2];
    c1 += (tq*2 + 1 < NBIN) ? lhist[(qb + u)*NBIN + tq*2 + 1] : 0u;
  }
  int S = (int)(c0 + c1);
#pragma unroll
  for (int d = 1; d < 16; d <<= 1) {
    int v = __shfl_down(S, d, 16);
    S += (tq + d < 16) ? v : 0;
  }
  int g = -1;
  if (S >= KNN) g = 2*tq;
  if (S - (int)c0 >= KNN) g = 2*tq + 1;
#pragma unroll
  for (int m = 1; m < 16; m <<= 1) g = max(g, __shfl_xor(g, m, 16));
  if (tq == 0) {
    uint K = (uint)(ktop - g);
    t2[q] = __uint_as_float((K << 21) | 0x1FFFFFu);
  }
}

// ---------------- Kernel 2b: full scan -> direct candidate extraction ----------------
// Gram test in registers (4-fma chain + cmp + addc = 6 VALU/pair), 16 mask words per
// thread in regs, then local extract loop (~4.7 hits/thread) -> atomic list append.
__global__ __launch_bounds__(256) void k2b_ext(
    const float4* __restrict__ s4, const float* __restrict__ t2,
    uint* __restrict__ cnt, unsigned short* __restrict__ cand) {
  __shared__ float4 tile4[128];
  __shared__ float  tileb[128];
  const int t  = threadIdx.x;
  const int c  = blockIdx.x >> 4;   // 128 chunks
  const int ig = blockIdx.x & 15;   // 16 query groups of 1024
  if (t < 128) {
    float4 p = s4[c*128 + t];
    tile4[t] = p;
    tileb[t] = 0.5f*(p.x*p.x + p.y*p.y + p.z*p.z + p.w*p.w);
  }
  const int q0 = ig*1024 + t;
  float4 sq[4]; float ui[4];
#pragma unroll
  for (int m = 0; m < 4; ++m) {
    int q = q0 + m*256;
    float4 s = s4[q];
    sq[m] = s;
    float n2 = s.x*s.x + s.y*s.y + s.z*s.z + s.w*s.w;
    ui[m] = 0.5f*(n2 - t2[q]) - 4e-6f;
  }
  __syncthreads();
  uint msk[4][4];
#pragma unroll 1
  for (int w = 0; w < 4; ++w) {
    uint mk0 = 0u, mk1 = 0u, mk2 = 0u, mk3 = 0u;
#pragma unroll
    for (int bit = 31; bit >= 0; --bit) {
      float4 p = tile4[w*32 + bit];
      float nb = tileb[w*32 + bit];
      float a0 = fmaf(sq[0].x, p.x, fmaf(sq[0].y, p.y, fmaf(sq[0].z, p.z, fmaf(sq[0].w, p.w, -nb))));
      float a1 = fmaf(sq[1].x, p.x, fmaf(sq[1].y, p.y, fmaf(sq[1].z, p.z, fmaf(sq[1].w, p.w, -nb))));
      float a2 = fmaf(sq[2].x, p.x, fmaf(sq[2].y, p.y, fmaf(sq[2].z, p.z, fmaf(sq[2].w, p.w, -nb))));
      float a3 = fmaf(sq[3].x, p.x, fmaf(sq[3].y, p.y, fmaf(sq[3].z, p.z, fmaf(sq[3].w, p.w, -nb))));
      mk0 = mk0 + mk0 + (a0 >= ui[0] ? 1u : 0u);
      mk1 = mk1 + mk1 + (a1 >= ui[1] ? 1u : 0u);
      mk2 = mk2 + mk2 + (a2 >= ui[2] ? 1u : 0u);
      mk3 = mk3 + mk3 + (a3 >= ui[3] ? 1u : 0u);
    }
    msk[0][w] = mk0; msk[1][w] = mk1; msk[2][w] = mk2; msk[3][w] = mk3;
  }
  // local extract + atomic append (expected ~1.2 hits per thread per m)
#pragma unroll 1
  for (int m = 0; m < 4; ++m) {
    const int q = q0 + m*256;
#pragma unroll 1
    for (int w = 0; w < 4; ++w) {
      uint bits = msk[m][w];
      while (bits) {
        int b = __builtin_ctz(bits); bits &= bits - 1;
        uint pos = atomicAdd(&cnt[q], 1u);
        if (pos < QCAP) cand[(size_t)q*QCAP + pos] = (unsigned short)(c*128 + w*32 + b);
      }
    }
  }
}

// ---------------- Kernel 3: rank-based selection from candidate lists + aggregation ---------
// block = 8 queries x 32 lanes. kmax-anchored class histogram (clamp-consistent).
__global__ __launch_bounds__(256) void k3_sel3(
    const float4* __restrict__ s4, const float* __restrict__ h,
    const uint* __restrict__ cntg, const unsigned short* __restrict__ cand,
    float* __restrict__ agg) {
  __shared__ u64  keys[QPB*QCAP];       // 32 KB
  __shared__ u64  qbuf[QPB*MCAP];       // 8 KB
  __shared__ u64  win[QPB*KNN];         // 1 KB
  __shared__ uint hist[QPB*32];         // 1 KB
  __shared__ uint mc[QPB];
  const int t  = threadIdx.x;
  const int ql = t >> 5, ln = t & 31;
  const int q  = blockIdx.x*QPB + ql;
  if (ln == 0) mc[ql] = 0u;
  hist[ql*32 + ln] = 0u;
  if (ln < KNN) win[ql*KNN + ln] = 0ull;
  const float4 sq = s4[q];
  const int cnt = min((int)cntg[q], QCAP);
  __syncthreads();
  // ---- exact keys (u64 = d2bits<<14 | j) + max class ----
  uint kmax = 0u;
  for (int u = ln; u < cnt; u += 32) {
    int j = cand[(size_t)q*QCAP + u];
    float e = d2f(sq, s4[j]);
    uint db = __float_as_uint(e);
    keys[ql*QCAP + u] = ((u64)db << 14) | (uint)j;
    kmax = max(kmax, db >> 21);
  }
#pragma unroll
  for (int m = 1; m < 32; m <<= 1) kmax = max(kmax, (uint)__shfl_xor((int)kmax, m, 32));
  for (int u = ln; u < cnt; u += 32) {
    uint cls = (uint)(keys[ql*QCAP + u] >> 35);
    uint rel = min(kmax - cls, 31u);
    atomicAdd(&hist[ql*32 + rel], 1u);
  }
  __syncthreads();
  // ---- boundary: largest r* with cum(r*) >= need; bcls = kmax - r* ----
  uint cum = hist[ql*32 + ln];
#pragma unroll
  for (int d = 1; d < 32; d <<= 1) {
    uint v = (uint)__shfl_down((int)cum, d, 32);
    if (ln + d < 32) cum += v;
  }
  const uint need = (uint)(cnt < KNN ? cnt : KNN);
  u64 bal = __ballot(cum >= need);
  uint half = (uint)(bal >> (((t >> 5) & 1) * 32));
  const uint rstar = 31u - (uint)__builtin_clz(half);
  const uint bcls = kmax - rstar;
  // ---- compact qualifier keys ----
  for (int u = ln; u < cnt; u += 32) {
    u64 key = keys[ql*QCAP + u];
    if ((uint)(key >> 35) <= bcls) {
      uint pos = atomicAdd(&mc[ql], 1u);
      if (pos < MCAP) qbuf[ql*MCAP + pos] = key;
    }
  }
  __syncthreads();
  const int mcnt = (int)mc[ql];
  if (mcnt <= MCAP) {
    for (int w = ln; w < mcnt; w += 32) {
      u64 key = qbuf[ql*MCAP + w];
      int rank = 0;
      for (int v = 0; v < mcnt; ++v) rank += (qbuf[ql*MCAP + v] < key) ? 1 : 0;
      if (rank < KNN) win[ql*KNN + rank] = key;
    }
  } else {
    for (int u = ln; u < cnt; u += 32) {
      u64 key = keys[ql*QCAP + u];
      if ((uint)(key >> 35) <= bcls) {
        int rank = 0;
        for (int v = 0; v < cnt; ++v) rank += (keys[ql*QCAP + v] < key) ? 1 : 0;
        if (rank < KNN) win[ql*KNN + rank] = key;
      }
    }
  }
  __syncthreads();
  // ---- aggregation: lane = h component, winners in rank order ----
  float sum = 0.f, mx = -FLTMAX;
#pragma unroll 1
  for (int r = 0; r < KNN; ++r) {
    u64 key = win[ql*KNN + r];
    float d2 = __uint_as_float((uint)(key >> 14));
    int j = (int)(key & 16383u);
    float w = __expf(-10.f * d2);
    float m = w * h[(size_t)j*PD + ln];
    sum += m; mx = fmaxf(mx, m);
  }
  agg[(size_t)q*64 + ln]      = sum * 0.0625f;
  agg[(size_t)q*64 + 32 + ln] = mx;
}

// ================= Fallback path (round-2, proven) =================
__global__ __launch_bounds__(256) void k2_knn_fb(
    const float4* __restrict__ s4, unsigned short* __restrict__ cand_j) {
  __shared__ float4 tile[TJF];
  __shared__ int    lbuf[256*33];
  const int t  = threadIdx.x;
  const int ib = blockIdx.x & 31;
  const int jc = blockIdx.x >> 5;
  const int jbase = jc * TJF;
#pragma unroll
  for (int g = 0; g < 4; ++g) tile[g*256 + t] = s4[jbase + g*256 + t];
  const int ia = ib*256 + t;
  const int ic = ia + 8192;
  const float4 sa = s4[ia];
  const float4 sc = s4[ic];
  __syncthreads();
  float va[KNN], vb[KNN]; int ja[KNN], jb[KNN];
#pragma unroll
  for (int q = 0; q < KNN; ++q) { va[q] = FLTMAX; ja[q] = 0; vb[q] = FLTMAX; jb[q] = 0; }
  float cma = FLTMAX, cmb = FLTMAX;
  int cpa = 0, cpb = 0, ca = 0, cb = 0;
  auto insertA = [&](float e, int jj) {
#pragma unroll
    for (int q = 0; q < KNN; ++q) if (q == cpa) { va[q] = e; ja[q] = jj; }
    cma = va[0]; cpa = 0;
#pragma unroll
    for (int q = 1; q < KNN; ++q) { if (va[q] > cma) { cma = va[q]; cpa = q; } }
  };
  auto insertB = [&](float e, int jj) {
#pragma unroll
    for (int q = 0; q < KNN; ++q) if (q == cpb) { vb[q] = e; jb[q] = jj; }
    cmb = vb[0]; cpb = 0;
#pragma unroll
    for (int q = 1; q < KNN; ++q) { if (vb[q] > cmb) { cmb = vb[q]; cpb = q; } }
  };
  auto compactA = [&]() {
    for (int u = 0; u < ca; ++u) {
      int jj = lbuf[t*33 + u];
      float e = d2f(sa, tile[jj]);
      if (e < cma) insertA(e, jj);
    }
    ca = 0;
  };
  auto compactB = [&]() {
    for (int u = 0; u < cb; ++u) {
      int jj = lbuf[t*33 + 16 + u];
      float e = d2f(sc, tile[jj]);
      if (e < cmb) insertB(e, jj);
    }
    cb = 0;
  };
  for (int ob = 0; ob < TJF/8; ++ob) {
#pragma unroll
    for (int u = 0; u < 8; ++u) {
      int jj = ob*8 + u;
      float4 p = tile[jj];
      float ea = d2f(sa, p);
      float eb = d2f(sc, p);
      if (ea < cma) { lbuf[t*33 + ca] = jj; ++ca; }
      if (eb < cmb) { lbuf[t*33 + 16 + cb] = jj; ++cb; }
    }
    if (__any(ca > 8)) compactA();
    if (__any(cb > 8)) compactB();
  }
  compactA(); compactB();
#pragma unroll
  for (int q = 0; q < KNN; ++q) {
    int c = jc*KNN + q;
    cand_j[(size_t)c*NPTS + ia] = (unsigned short)(ja[q] + jbase);
    cand_j[(size_t)c*NPTS + ic] = (unsigned short)(jb[q] + jbase);
  }
}

__global__ __launch_bounds__(256) void k3_merge_fb(
    const float4* __restrict__ s4, const float4* __restrict__ h4,
    const unsigned short* __restrict__ cand_j, float* __restrict__ agg) {
  __shared__ float le[64*67];
  __shared__ int   lj[64*67];
  const int t  = threadIdx.x;
  const int il = t & 63, tq = t >> 6;
  const int i  = blockIdx.x*64 + il;
  const float4 si = s4[i];
  float val[KNN]; int vid[KNN];
#pragma unroll
  for (int q = 0; q < KNN; ++q) { val[q] = FLTMAX; vid[q] = 0; }
  float cmax = FLTMAX; int cpos = 0;
  for (int u = 0; u < 64; ++u) {
    int c = tq*64 + u;
    int j = cand_j[(size_t)c*NPTS + i];
    float e = d2f(si, s4[j]);
    if (e < cmax) {
#pragma unroll
      for (int q = 0; q < KNN; ++q) if (q == cpos) { val[q] = e; vid[q] = j; }
      cmax = val[0]; cpos = 0;
#pragma unroll
      for (int q = 1; q < KNN; ++q) { if (val[q] > cmax) { cmax = val[q]; cpos = q; } }
    }
  }
#pragma unroll
  for (int q = 0; q < KNN; ++q) {
    le[il*67 + tq*16 + q] = val[q];
    lj[il*67 + tq*16 + q] = vid[q];
  }
  __syncthreads();
  if (t < 64) {
    float mv[KNN]; int mj[KNN];
#pragma unroll
    for (int q = 0; q < KNN; ++q) { mv[q] = FLTMAX; mj[q] = 0; }
    float cm2 = FLTMAX; int cp2 = 0;
    for (int u = 0; u < 64; ++u) {
      float e = le[t*67 + u];
      int   j = lj[t*67 + u];
      if (e < cm2) {
#pragma unroll
        for (int q = 0; q < KNN; ++q) if (q == cp2) { mv[q] = e; mj[q] = j; }
        cm2 = mv[0]; cp2 = 0;
#pragma unroll
        for (int q = 1; q < KNN; ++q) { if (mv[q] > cm2) { cm2 = mv[q]; cp2 = q; } }
      }
    }
#pragma unroll
    for (int q = 0; q < KNN; ++q) {
      le[t*67 + q] = __expf(-10.f * mv[q]);
      lj[t*67 + q] = mj[q];
    }
  }
  __syncthreads();
  float ms[8], mm[8];
#pragma unroll
  for (int p = 0; p < 8; ++p) { ms[p] = 0.f; mm[p] = -FLTMAX; }
#pragma unroll 1
  for (int q = 0; q < KNN; ++q) {
    float w = le[il*67 + q];
    int   j = lj[il*67 + q];
    float4 a = h4[(size_t)j*8 + tq*2];
    float4 b = h4[(size_t)j*8 + tq*2 + 1];
    float m0 = a.x*w, m1 = a.y*w, m2 = a.z*w, m3 = a.w*w;
    float m4 = b.x*w, m5 = b.y*w, m6 = b.z*w, m7 = b.w*w;
    ms[0] += m0; mm[0] = fmaxf(mm[0], m0);
    ms[1] += m1; mm[1] = fmaxf(mm[1], m1);
    ms[2] += m2; mm[2] = fmaxf(mm[2], m2);
    ms[3] += m3; mm[3] = fmaxf(mm[3], m3);
    ms[4] += m4; mm[4] = fmaxf(mm[4], m4);
    ms[5] += m5; mm[5] = fmaxf(mm[5], m5);
    ms[6] += m6; mm[6] = fmaxf(mm[6], m6);
    ms[7] += m7; mm[7] = fmaxf(mm[7], m7);
  }
  float4 o0 = make_float4(ms[0]*0.0625f, ms[1]*0.0625f, ms[2]*0.0625f, ms[3]*0.0625f);
  float4 o1 = make_float4(ms[4]*0.0625f, ms[5]*0.0625f, ms[6]*0.0625f, ms[7]*0.0625f);
  *(float4*)&agg[(size_t)i*64 + tq*8]      = o0;
  *(float4*)&agg[(size_t)i*64 + tq*8 + 4]  = o1;
  *(float4*)&agg[(size_t)i*64 + 32 + tq*8]     = make_float4(mm[0], mm[1], mm[2], mm[3]);
  *(float4*)&agg[(size_t)i*64 + 32 + tq*8 + 4] = make_float4(mm[4], mm[5], mm[6], mm[7]);
}

// ---------------- Kernel 4a: pack/transpose weights ----------------
__global__ __launch_bounds__(256) void k4a_wt(
    const float* __restrict__ W1, const float* __restrict__ W2, float* __restrict__ wT) {
  int idx = blockIdx.x*256 + threadIdx.x;
  if (idx >= 192*COUT) return;
  int k = idx >> 7, c = idx & 127;
  float v = (k < 128) ? W1[(size_t)c*128 + k] : W2[(size_t)c*64 + (k - 128)];
  wT[(size_t)k*COUT + c] = v;
}

// ---------------- Kernel 4: out = x@W1^T + agg@W2^T + b2 (32x128 tile, 4x4/thread) ----------
__global__ __launch_bounds__(256) void k4_out2(
    const float* __restrict__ x, const float* __restrict__ agg,
    const float* __restrict__ wT, const float* __restrict__ b2,
    float* __restrict__ out) {
  __shared__ float xa[32*192];
  const int t = threadIdx.x;
  const int row0 = blockIdx.x * 32;
#pragma unroll
  for (int g = 0; g < 4; ++g) {
    int fi = g*256 + t;
    int r = fi >> 5, c4 = fi & 31;
    *(float4*)&xa[r*192 + c4*4] = *(const float4*)&x[(size_t)(row0+r)*CIN + c4*4];
  }
#pragma unroll
  for (int g = 0; g < 2; ++g) {
    int fi = g*256 + t;
    int r = fi >> 4, c4 = fi & 15;
    *(float4*)&xa[r*192 + 128 + c4*4] = *(const float4*)&agg[(size_t)(row0+r)*64 + c4*4];
  }
  __syncthreads();
  const int c4 = t & 31;
  const int rg = t >> 5;
  float acc[4][4];
#pragma unroll
  for (int r = 0; r < 4; ++r) { acc[r][0]=0.f; acc[r][1]=0.f; acc[r][2]=0.f; acc[r][3]=0.f; }
  for (int k = 0; k < 192; k += 4) {
    float4 w0 = *(const float4*)&wT[(size_t)(k+0)*COUT + c4*4];
    float4 w1 = *(const float4*)&wT[(size_t)(k+1)*COUT + c4*4];
    float4 w2 = *(const float4*)&wT[(size_t)(k+2)*COUT + c4*4];
    float4 w3 = *(const float4*)&wT[(size_t)(k+3)*COUT + c4*4];
#pragma unroll
    for (int r = 0; r < 4; ++r) {
      float4 xv = *(const float4*)&xa[(rg*4 + r)*192 + k];
      acc[r][0] = fmaf(xv.x, w0.x, fmaf(xv.y, w1.x, fmaf(xv.z, w2.x, fmaf(xv.w, w3.x, acc[r][0]))));
      acc[r][1] = fmaf(xv.x, w0.y, fmaf(xv.y, w1.y, fmaf(xv.z, w2.y, fmaf(xv.w, w3.y, acc[r][1]))));
      acc[r][2] = fmaf(xv.x, w0.z, fmaf(xv.y, w1.z, fmaf(xv.z, w2.z, fmaf(xv.w, w3.z, acc[r][2]))));
      acc[r][3] = fmaf(xv.x, w0.w, fmaf(xv.y, w1.w, fmaf(xv.z, w2.w, fmaf(xv.w, w3.w, acc[r][3]))));
    }
  }
  float4 bias = *(const float4*)&b2[c4*4];
#pragma unroll
  for (int r = 0; r < 4; ++r) {
    float4 o = make_float4(acc[r][0]+bias.x, acc[r][1]+bias.y, acc[r][2]+bias.z, acc[r][3]+bias.w);
    *(float4*)&out[(size_t)(row0 + rg*4 + r)*COUT + c4*4] = o;
  }
}

extern "C" void kernel_launch(void* const* d_in, const int* in_sizes, int n_in,
                              void* d_out, int out_size, void* d_ws, size_t ws_size,
                              hipStream_t stream) {
  const float* x  = (const float*)d_in[0];
  const float* Ws = (const float*)d_in[1];
  const float* bs = (const float*)d_in[2];
  const float* Wh = (const float*)d_in[3];
  const float* bh = (const float*)d_in[4];
  const float* W1 = (const float*)d_in[5];
  const float* W2 = (const float*)d_in[6];
  const float* b2 = (const float*)d_in[7];
  float* out = (float*)d_out;

  char* ws = (char*)d_ws;
  float4* s4 = (float4*)(ws + WS_S4);
  float*  h  = (float*) (ws + WS_H);

  k1_proj<<<NPTS/64, 256, 0, stream>>>(x, Ws, bs, Wh, bh, s4, h);

  if (ws_size >= (size_t)WS_NEED) {
    float* t2  = (float*)(ws + WS_T2);
    uint*  cnt = (uint*) (ws + WS_CNT);
    float* agg = (float*)(ws + WS_AGG);
    float* wT  = (float*)(ws + WS_WT);
    unsigned short* cand = (unsigned short*)(ws + WS_CAND);
    k2t_thresh<<<NPTS/16, 256, 0, stream>>>(s4, t2);
    hipMemsetAsync(cnt, 0, NPTS*sizeof(uint), stream);
    k2b_ext<<<2048, 256, 0, stream>>>(s4, t2, cnt, cand);
    k3_sel3<<<NPTS/QPB, 256, 0, stream>>>(s4, h, cnt, cand, agg);
    k4a_wt<<<(192*COUT + 255)/256, 256, 0, stream>>>(W1, W2, wT);
    k4_out2<<<NPTS/32, 256, 0, stream>>>(x, agg, wT, b2, out);
  } else {
    unsigned short* cj = (unsigned short*)(ws + WS_CJ_F);
    float* agg = (float*)(ws + WS_AGG_F);
    float* wT  = (float*)(ws + WS_WT_F);
    k2_knn_fb<<<512, 256, 0, stream>>>(s4, cj);
    k3_merge_fb<<<NPTS/64, 256, 0, stream>>>(s4, (const float4*)h, cj, agg);
    k4a_wt<<<(192*COUT + 255)/256, 256, 0, stream>>>(W1, W2, wT);
    k4_out2<<<NPTS/32, 256, 0, stream>>>(x, agg, wT, b2, out);
  }
}

// Round 10
// 217.045 us; speedup vs baseline: 1.1443x; 1.1443x over previous
//
#include <hip/hip_runtime.h>
#include <hip/hip_bf16.h>

// GravNetConv: N=16384, C_IN=128, S=4, P=32, K=16, C_OUT=128.
// Mask path: [k1] proj (fp64 s) -> [k2t] threshold via radix-ladder histogram ->
// [k2b] full N^2 Gram-form scan, mask words in REGISTERS, one coalesced uint4 store
// per (chunk,query) (no atomics, no write amplification) -> [k3_sel2] rank-based
// recovery (kmax-anchored class histogram) -> coalesced aggregation ->
// [k4a/k4_out2] out = x@W1^T + agg@W2^T + b2.
// Fallback path (ws_size < 41MB): round-2 kernels.

#define NPTS 16384
#define CIN  128
#define SD   4
#define PD   32
#define KNN  16
#define COUT 128
#define FLTMAX 3.4028234663852886e+38f
#define NBIN 33
#define QPB  8      // k3 queries per block
#define QCAP 512    // k3 per-query candidate cap
#define MCAP 128    // k3 per-query qualifier cap (fallback scan if exceeded)

typedef float v2f __attribute__((ext_vector_type(2)));
typedef unsigned int uint;
typedef unsigned long long u64;

// ---- shared offsets (both paths) ----
#define WS_S4     0            // N * float4 = 256 KB
#define WS_H      0x40000      // N * 32 f32 = 2 MB
// ---- mask-path offsets ----
#define WS_AGG_M  0x280000     // [N][64] f32 = 4 MB
#define WS_WT_M   0x680000     // [192][128] f32 = 96 KB
#define WS_T2     0x6A0000     // N f32 = 64 KB
#define WS_MASK   0x700000     // 128 chunks * N uint4 = 32 MB
#define WS_NEED_M 0x2700000    // 40.9 MB
// ---- fallback offsets ----
#define WS_CJ_F   0x400000
#define WS_AGG_F  0xC00000
#define WS_WT_F   0x1000000
#define JS   16
#define TJF  (NPTS/JS)

__device__ __forceinline__ float d2f(const float4 a, const float4 b) {
  v2f d0 = {a.x - b.x, a.y - b.y};
  v2f d1 = {a.z - b.z, a.w - b.w};
  v2f pr = d0*d0 + d1*d1;
  return pr.x + pr.y;
}

// ---------------- Kernel 1: s (fp64 accumulate) and h projections ----------------
__global__ __launch_bounds__(256) void k1_proj(
    const float* __restrict__ x, const float* __restrict__ Ws, const float* __restrict__ bs,
    const float* __restrict__ Wh, const float* __restrict__ bh,
    float4* __restrict__ s4, float* __restrict__ h) {
  __shared__ float  lw[36*128];
  __shared__ float  lx[64*132];
  __shared__ double rs[3*64*5];
  __shared__ float  rh[3*64*33];
  const int t = threadIdx.x;
  const int row0 = blockIdx.x * 64;
  for (int i2 = t; i2 < 36*128; i2 += 256)
    lw[i2] = (i2 < 512) ? Ws[i2] : Wh[i2 - 512];
#pragma unroll
  for (int g = 0; g < 8; ++g) {
    int fi = g*256 + t;
    int r = fi >> 5, c4 = fi & 31;
    *(float4*)&lx[r*132 + c4*4] = *(const float4*)&x[(size_t)(row0 + r)*CIN + c4*4];
  }
  __syncthreads();
  const int kq = t >> 6;
  const int r  = t & 63;
  const int kb = kq * 32;
  double sacc[4] = {0.0, 0.0, 0.0, 0.0};
  float  hacc[32];
#pragma unroll
  for (int p = 0; p < 32; ++p) hacc[p] = 0.f;
#pragma unroll
  for (int k4 = 0; k4 < 8; ++k4) {
    float4 xv = *(const float4*)&lx[r*132 + kb + k4*4];
    int kg = kb + k4*4;
#pragma unroll
    for (int p = 0; p < 4; ++p) {
      float4 wv = *(const float4*)&lw[p*128 + kg];
      sacc[p] = fma((double)xv.x, (double)wv.x, sacc[p]);
      sacc[p] = fma((double)xv.y, (double)wv.y, sacc[p]);
      sacc[p] = fma((double)xv.z, (double)wv.z, sacc[p]);
      sacc[p] = fma((double)xv.w, (double)wv.w, sacc[p]);
    }
#pragma unroll
    for (int p = 0; p < 32; ++p) {
      float4 wv = *(const float4*)&lw[(4+p)*128 + kg];
      hacc[p] = fmaf(xv.x, wv.x, fmaf(xv.y, wv.y, fmaf(xv.z, wv.z, fmaf(xv.w, wv.w, hacc[p]))));
    }
  }
  if (kq > 0) {
    const int bq = kq - 1;
#pragma unroll
    for (int d = 0; d < 4; ++d) rs[(bq*64 + r)*5 + d] = sacc[d];
#pragma unroll
    for (int p = 0; p < 32; ++p) rh[(bq*64 + r)*33 + p] = hacc[p];
  }
  __syncthreads();
  if (kq == 0) {
    const int row = row0 + r;
    float so[4];
#pragma unroll
    for (int d = 0; d < 4; ++d) {
      double sd = sacc[d] + rs[(0*64 + r)*5 + d] + rs[(1*64 + r)*5 + d]
                + rs[(2*64 + r)*5 + d] + (double)bs[d];
      so[d] = (float)sd;
    }
    s4[row] = make_float4(so[0], so[1], so[2], so[3]);
#pragma unroll
    for (int p4 = 0; p4 < 8; ++p4) {
      float o[4];
#pragma unroll
      for (int c = 0; c < 4; ++c) {
        int p = p4*4 + c;
        o[c] = hacc[p] + rh[(0*64 + r)*33 + p] + rh[(1*64 + r)*33 + p]
             + rh[(2*64 + r)*33 + p] + bh[p];
      }
      *(float4*)&h[(size_t)row*PD + p4*4] = make_float4(o[0], o[1], o[2], o[3]);
    }
  }
}

// ---------------- Kernel 2t: per-query threshold via radix-ladder histogram ----------------
__global__ __launch_bounds__(256) void k2t_thresh(
    const float4* __restrict__ s4, float* __restrict__ t2) {
  __shared__ float4 tile[2064];
  __shared__ uint   lhist[256*NBIN];
  const int t = threadIdx.x;
#pragma unroll
  for (int g = 0; g < 8; ++g) {
    int j = g*256 + t;
    tile[j + (j >> 7)] = s4[j];
  }
#pragma unroll
  for (int b = 0; b < NBIN; ++b) lhist[t*NBIN + b] = 0u;
  const int ql = t >> 4, tq = t & 15;
  const int q  = blockIdx.x*16 + ql;
  const float4 sq = s4[q];
  __syncthreads();
  float tau = d2f(sq, tile[tq*129]);
#pragma unroll
  for (int m = 1; m < 16; m <<= 1) tau = fmaxf(tau, __shfl_xor(tau, m, 16));
  const int ktop = (int)(__float_as_uint(tau) >> 21);
  const int hb = t*NBIN;
#pragma unroll 4
  for (int u = 0; u < 128; ++u) {
    float4 p = tile[tq*129 + u];
    float e = d2f(sq, p);
    int key = (int)(__float_as_uint(e) >> 21);
    int rel = ktop - key;
    rel = rel < 0 ? 0 : (rel > 32 ? 32 : rel);
    atomicAdd(&lhist[hb + rel], 1u);
  }
  __syncthreads();
  uint c0 = 0, c1 = 0;
  const int qb = ql*16;
  for (int u = 0; u < 16; ++u) {
    c0 += lhist[(qb + u)*NBIN + tq*2];
    c1 += (tq*2 + 1 < NBIN) ? lhist[(qb + u)*NBIN + tq*2 + 1] : 0u;
  }
  int S = (int)(c0 + c1);
#pragma unroll
  for (int d = 1; d < 16; d <<= 1) {
    int v = __shfl_down(S, d, 16);
    S += (tq + d < 16) ? v : 0;
  }
  int g = -1;
  if (S >= KNN) g = 2*tq;
  if (S - (int)c0 >= KNN) g = 2*tq + 1;
#pragma unroll
  for (int m = 1; m < 16; m <<= 1) g = max(g, __shfl_xor(g, m, 16));
  if (tq == 0) {
    uint K = (uint)(ktop - g);
    t2[q] = __uint_as_float((K << 21) | 0x1FFFFFu);
  }
}

// ---------------- Kernel 2b: full scan -> bitmask; register mask words, uint4 store -------
// Gram test: d2 <= t2+eps  <=>  si.sj - bj >= ui  (4-fma chain + cmp + addc = 6 VALU/pair).
// One coalesced uint4 store per (c,q): no write amplification, no atomics.
__global__ __launch_bounds__(256) void k2b_mask(
    const float4* __restrict__ s4, const float* __restrict__ t2, uint4* __restrict__ maskw) {
  __shared__ float4 tile4[128];
  __shared__ float  tileb[128];
  const int t  = threadIdx.x;
  const int c  = blockIdx.x >> 4;   // 128 chunks
  const int ig = blockIdx.x & 15;   // 16 query groups of 1024
  if (t < 128) {
    float4 p = s4[c*128 + t];
    tile4[t] = p;
    tileb[t] = 0.5f*(p.x*p.x + p.y*p.y + p.z*p.z + p.w*p.w);
  }
  const int q0 = ig*1024 + t;
  float4 sq[4]; float ui[4];
#pragma unroll
  for (int m = 0; m < 4; ++m) {
    int q = q0 + m*256;
    float4 s = s4[q];
    sq[m] = s;
    float n2 = s.x*s.x + s.y*s.y + s.z*s.z + s.w*s.w;
    ui[m] = 0.5f*(n2 - t2[q]) - 4e-6f;
  }
  __syncthreads();
  uint msk[4][4];
#pragma unroll 1
  for (int w = 0; w < 4; ++w) {
    uint mk0 = 0u, mk1 = 0u, mk2 = 0u, mk3 = 0u;
#pragma unroll
    for (int bit = 31; bit >= 0; --bit) {
      float4 p = tile4[w*32 + bit];
      float nb = tileb[w*32 + bit];
      float a0 = fmaf(sq[0].x, p.x, fmaf(sq[0].y, p.y, fmaf(sq[0].z, p.z, fmaf(sq[0].w, p.w, -nb))));
      float a1 = fmaf(sq[1].x, p.x, fmaf(sq[1].y, p.y, fmaf(sq[1].z, p.z, fmaf(sq[1].w, p.w, -nb))));
      float a2 = fmaf(sq[2].x, p.x, fmaf(sq[2].y, p.y, fmaf(sq[2].z, p.z, fmaf(sq[2].w, p.w, -nb))));
      float a3 = fmaf(sq[3].x, p.x, fmaf(sq[3].y, p.y, fmaf(sq[3].z, p.z, fmaf(sq[3].w, p.w, -nb))));
      mk0 = mk0 + mk0 + (a0 >= ui[0] ? 1u : 0u);
      mk1 = mk1 + mk1 + (a1 >= ui[1] ? 1u : 0u);
      mk2 = mk2 + mk2 + (a2 >= ui[2] ? 1u : 0u);
      mk3 = mk3 + mk3 + (a3 >= ui[3] ? 1u : 0u);
    }
    msk[0][w] = mk0; msk[1][w] = mk1; msk[2][w] = mk2; msk[3][w] = mk3;
  }
#pragma unroll
  for (int m = 0; m < 4; ++m) {
    int q = q0 + m*256;
    maskw[(size_t)c*NPTS + q] = make_uint4(msk[m][0], msk[m][1], msk[m][2], msk[m][3]);
  }
}

// ---------------- Kernel 3: rank-based recovery + aggregation (mask input) ----------------
// block = 8 queries x 32 lanes. Lane covers chunks [4*ln, 4*ln+4).
// kmax-anchored class histogram: rel = min(kmax-cls, 31); clamp-consistent predicate.
__global__ __launch_bounds__(256) void k3_sel2(
    const float4* __restrict__ s4, const float* __restrict__ h,
    const uint4* __restrict__ maskw, float* __restrict__ agg) {
  __shared__ u64  qbuf[QPB*MCAP];       // 8 KB; aliased below as u16 j-list
  __shared__ u64  keys[QPB*QCAP];       // 32 KB
  __shared__ u64  win[QPB*KNN];         // 1 KB
  __shared__ uint hist[QPB*32];         // 1 KB
  __shared__ uint cnts[QPB];
  __shared__ uint mc[QPB];
  unsigned short* jl = (unsigned short*)qbuf;   // QPB*QCAP u16 = 8 KB (exact alias)
  const int t  = threadIdx.x;
  const int ql = t >> 5, ln = t & 31;
  const int q  = blockIdx.x*QPB + ql;
  if (ln == 0) { cnts[ql] = 0u; mc[ql] = 0u; }
  hist[ql*32 + ln] = 0u;
  if (ln < KNN) win[ql*KNN + ln] = 0ull;
  const float4 sq = s4[q];
  __syncthreads();
  // ---- phase A: extract candidate j's (order-free compaction) ----
  uint wv[16]; int pc = 0;
#pragma unroll
  for (int u = 0; u < 4; ++u) {
    const int c = ln*4 + u;
    uint4 m4 = maskw[(size_t)c*NPTS + q];
    wv[u*4+0] = m4.x; wv[u*4+1] = m4.y; wv[u*4+2] = m4.z; wv[u*4+3] = m4.w;
    pc += __popc(m4.x) + __popc(m4.y) + __popc(m4.z) + __popc(m4.w);
  }
  int base = (int)atomicAdd(&cnts[ql], (uint)pc);
#pragma unroll
  for (int w = 0; w < 16; ++w) {
    uint bits = wv[w];
    const int jb = (ln*4 + (w >> 2))*128 + (w & 3)*32;
    while (bits) {
      int b = __builtin_ctz(bits); bits &= bits - 1;
      if (base < QCAP) jl[ql*QCAP + base] = (unsigned short)(jb + b);
      ++base;
    }
  }
  __syncthreads();
  const int cnt = min((int)cnts[ql], QCAP);
  // ---- phase B: exact keys (u64 = d2bits<<14 | j) + max class ----
  uint kmax = 0u;
  for (int u = ln; u < cnt; u += 32) {
    int j = jl[ql*QCAP + u];
    float e = d2f(sq, s4[j]);
    uint db = __float_as_uint(e);
    keys[ql*QCAP + u] = ((u64)db << 14) | (uint)j;
    kmax = max(kmax, db >> 21);
  }
#pragma unroll
  for (int m = 1; m < 32; m <<= 1) kmax = max(kmax, (uint)__shfl_xor((int)kmax, m, 32));
  for (int u = ln; u < cnt; u += 32) {
    uint cls = (uint)(keys[ql*QCAP + u] >> 35);
    uint rel = min(kmax - cls, 31u);
    atomicAdd(&hist[ql*32 + rel], 1u);
  }
  __syncthreads();
  // ---- boundary: largest r* with cum(r*) >= need; bcls = kmax - r* ----
  uint cum = hist[ql*32 + ln];
#pragma unroll
  for (int d = 1; d < 32; d <<= 1) {
    uint v = (uint)__shfl_down((int)cum, d, 32);
    if (ln + d < 32) cum += v;
  }
  const uint need = (uint)(cnt < KNN ? cnt : KNN);
  u64 bal = __ballot(cum >= need);
  uint half = (uint)(bal >> (((t >> 5) & 1) * 32));
  const uint rstar = 31u - (uint)__builtin_clz(half);
  const uint bcls = kmax - rstar;
  // ---- compact qualifier keys into qbuf (aliases jl; jl reads are done) ----
  __syncthreads();
  for (int u = ln; u < cnt; u += 32) {
    u64 key = keys[ql*QCAP + u];
    if ((uint)(key >> 35) <= bcls) {
      uint pos = atomicAdd(&mc[ql], 1u);
      if (pos < MCAP) qbuf[ql*MCAP + pos] = key;
    }
  }
  __syncthreads();
  const int mcnt = (int)mc[ql];
  if (mcnt <= MCAP) {
    for (int w = ln; w < mcnt; w += 32) {
      u64 key = qbuf[ql*MCAP + w];
      int rank = 0;
      for (int v = 0; v < mcnt; ++v) rank += (qbuf[ql*MCAP + v] < key) ? 1 : 0;
      if (rank < KNN) win[ql*KNN + rank] = key;
    }
  } else {
    for (int u = ln; u < cnt; u += 32) {
      u64 key = keys[ql*QCAP + u];
      if ((uint)(key >> 35) <= bcls) {
        int rank = 0;
        for (int v = 0; v < cnt; ++v) rank += (keys[ql*QCAP + v] < key) ? 1 : 0;
        if (rank < KNN) win[ql*KNN + rank] = key;
      }
    }
  }
  __syncthreads();
  // ---- aggregation: lane = h component, winners in rank order ----
  float sum = 0.f, mx = -FLTMAX;
#pragma unroll 1
  for (int r = 0; r < KNN; ++r) {
    u64 key = win[ql*KNN + r];
    float d2 = __uint_as_float((uint)(key >> 14));
    int j = (int)(key & 16383u);
    float w = __expf(-10.f * d2);
    float m = w * h[(size_t)j*PD + ln];
    sum += m; mx = fmaxf(mx, m);
  }
  agg[(size_t)q*64 + ln]      = sum * 0.0625f;
  agg[(size_t)q*64 + 32 + ln] = mx;
}

// ================= Fallback path (round-2, proven) =================
__global__ __launch_bounds__(256) void k2_knn_fb(
    const float4* __restrict__ s4, unsigned short* __restrict__ cand_j) {
  __shared__ float4 tile[TJF];
  __shared__ int    lbuf[256*33];
  const int t  = threadIdx.x;
  const int ib = blockIdx.x & 31;
  const int jc = blockIdx.x >> 5;
  const int jbase = jc * TJF;
#pragma unroll
  for (int g = 0; g < 4; ++g) tile[g*256 + t] = s4[jbase + g*256 + t];
  const int ia = ib*256 + t;
  const int ic = ia + 8192;
  const float4 sa = s4[ia];
  const float4 sc = s4[ic];
  __syncthreads();
  float va[KNN], vb[KNN]; int ja[KNN], jb[KNN];
#pragma unroll
  for (int q = 0; q < KNN; ++q) { va[q] = FLTMAX; ja[q] = 0; vb[q] = FLTMAX; jb[q] = 0; }
  float cma = FLTMAX, cmb = FLTMAX;
  int cpa = 0, cpb = 0, ca = 0, cb = 0;
  auto insertA = [&](float e, int jj) {
#pragma unroll
    for (int q = 0; q < KNN; ++q) if (q == cpa) { va[q] = e; ja[q] = jj; }
    cma = va[0]; cpa = 0;
#pragma unroll
    for (int q = 1; q < KNN; ++q) { if (va[q] > cma) { cma = va[q]; cpa = q; } }
  };
  auto insertB = [&](float e, int jj) {
#pragma unroll
    for (int q = 0; q < KNN; ++q) if (q == cpb) { vb[q] = e; jb[q] = jj; }
    cmb = vb[0]; cpb = 0;
#pragma unroll
    for (int q = 1; q < KNN; ++q) { if (vb[q] > cmb) { cmb = vb[q]; cpb = q; } }
  };
  auto compactA = [&]() {
    for (int u = 0; u < ca; ++u) {
      int jj = lbuf[t*33 + u];
      float e = d2f(sa, tile[jj]);
      if (e < cma) insertA(e, jj);
    }
    ca = 0;
  };
  auto compactB = [&]() {
    for (int u = 0; u < cb; ++u) {
      int jj = lbuf[t*33 + 16 + u];
      float e = d2f(sc, tile[jj]);
      if (e < cmb) insertB(e, jj);
    }
    cb = 0;
  };
  for (int ob = 0; ob < TJF/8; ++ob) {
#pragma unroll
    for (int u = 0; u < 8; ++u) {
      int jj = ob*8 + u;
      float4 p = tile[jj];
      float ea = d2f(sa, p);
      float eb = d2f(sc, p);
      if (ea < cma) { lbuf[t*33 + ca] = jj; ++ca; }
      if (eb < cmb) { lbuf[t*33 + 16 + cb] = jj; ++cb; }
    }
    if (__any(ca > 8)) compactA();
    if (__any(cb > 8)) compactB();
  }
  compactA(); compactB();
#pragma unroll
  for (int q = 0; q < KNN; ++q) {
    int c = jc*KNN + q;
    cand_j[(size_t)c*NPTS + ia] = (unsigned short)(ja[q] + jbase);
    cand_j[(size_t)c*NPTS + ic] = (unsigned short)(jb[q] + jbase);
  }
}

__global__ __launch_bounds__(256) void k3_merge_fb(
    const float4* __restrict__ s4, const float4* __restrict__ h4,
    const unsigned short* __restrict__ cand_j, float* __restrict__ agg) {
  __shared__ float le[64*67];
  __shared__ int   lj[64*67];
  const int t  = threadIdx.x;
  const int il = t & 63, tq = t >> 6;
  const int i  = blockIdx.x*64 + il;
  const float4 si = s4[i];
  float val[KNN]; int vid[KNN];
#pragma unroll
  for (int q = 0; q < KNN; ++q) { val[q] = FLTMAX; vid[q] = 0; }
  float cmax = FLTMAX; int cpos = 0;
  for (int u = 0; u < 64; ++u) {
    int c = tq*64 + u;
    int j = cand_j[(size_t)c*NPTS + i];
    float e = d2f(si, s4[j]);
    if (e < cmax) {
#pragma unroll
      for (int q = 0; q < KNN; ++q) if (q == cpos) { val[q] = e; vid[q] = j; }
      cmax = val[0]; cpos = 0;
#pragma unroll
      for (int q = 1; q < KNN; ++q) { if (val[q] > cmax) { cmax = val[q]; cpos = q; } }
    }
  }
#pragma unroll
  for (int q = 0; q < KNN; ++q) {
    le[il*67 + tq*16 + q] = val[q];
    lj[il*67 + tq*16 + q] = vid[q];
  }
  __syncthreads();
  if (t < 64) {
    float mv[KNN]; int mj[KNN];
#pragma unroll
    for (int q = 0; q < KNN; ++q) { mv[q] = FLTMAX; mj[q] = 0; }
    float cm2 = FLTMAX; int cp2 = 0;
    for (int u = 0; u < 64; ++u) {
      float e = le[t*67 + u];
      int   j = lj[t*67 + u];
      if (e < cm2) {
#pragma unroll
        for (int q = 0; q < KNN; ++q) if (q == cp2) { mv[q] = e; mj[q] = j; }
        cm2 = mv[0]; cp2 = 0;
#pragma unroll
        for (int q = 1; q < KNN; ++q) { if (mv[q] > cm2) { cm2 = mv[q]; cp2 = q; } }
      }
    }
#pragma unroll
    for (int q = 0; q < KNN; ++q) {
      le[t*67 + q] = __expf(-10.f * mv[q]);
      lj[t*67 + q] = mj[q];
    }
  }
  __syncthreads();
  float ms[8], mm[8];
#pragma unroll
  for (int p = 0; p < 8; ++p) { ms[p] = 0.f; mm[p] = -FLTMAX; }
#pragma unroll 1
  for (int q = 0; q < KNN; ++q) {
    float w = le[il*67 + q];
    int   j = lj[il*67 + q];
    float4 a = h4[(size_t)j*8 + tq*2];
    float4 b = h4[(size_t)j*8 + tq*2 + 1];
    float m0 = a.x*w, m1 = a.y*w, m2 = a.z*w, m3 = a.w*w;
    float m4 = b.x*w, m5 = b.y*w, m6 = b.z*w, m7 = b.w*w;
    ms[0] += m0; mm[0] = fmaxf(mm[0], m0);
    ms[1] += m1; mm[1] = fmaxf(mm[1], m1);
    ms[2] += m2; mm[2] = fmaxf(mm[2], m2);
    ms[3] += m3; mm[3] = fmaxf(mm[3], m3);
    ms[4] += m4; mm[4] = fmaxf(mm[4], m4);
    ms[5] += m5; mm[5] = fmaxf(mm[5], m5);
    ms[6] += m6; mm[6] = fmaxf(mm[6], m6);
    ms[7] += m7; mm[7] = fmaxf(mm[7], m7);
  }
  float4 o0 = make_float4(ms[0]*0.0625f, ms[1]*0.0625f, ms[2]*0.0625f, ms[3]*0.0625f);
  float4 o1 = make_float4(ms[4]*0.0625f, ms[5]*0.0625f, ms[6]*0.0625f, ms[7]*0.0625f);
  *(float4*)&agg[(size_t)i*64 + tq*8]      = o0;
  *(float4*)&agg[(size_t)i*64 + tq*8 + 4]  = o1;
  *(float4*)&agg[(size_t)i*64 + 32 + tq*8]     = make_float4(mm[0], mm[1], mm[2], mm[3]);
  *(float4*)&agg[(size_t)i*64 + 32 + tq*8 + 4] = make_float4(mm[4], mm[5], mm[6], mm[7]);
}

// ---------------- Kernel 4a: pack/transpose weights ----------------
__global__ __launch_bounds__(256) void k4a_wt(
    const float* __restrict__ W1, const float* __restrict__ W2, float* __restrict__ wT) {
  int idx = blockIdx.x*256 + threadIdx.x;
  if (idx >= 192*COUT) return;
  int k = idx >> 7, c = idx & 127;
  float v = (k < 128) ? W1[(size_t)c*128 + k] : W2[(size_t)c*64 + (k - 128)];
  wT[(size_t)k*COUT + c] = v;
}

// ---------------- Kernel 4: out = x@W1^T + agg@W2^T + b2 (32x128 tile, 4x4/thread) ----------
__global__ __launch_bounds__(256) void k4_out2(
    const float* __restrict__ x, const float* __restrict__ agg,
    const float* __restrict__ wT, const float* __restrict__ b2,
    float* __restrict__ out) {
  __shared__ float xa[32*192];
  const int t = threadIdx.x;
  const int row0 = blockIdx.x * 32;
#pragma unroll
  for (int g = 0; g < 4; ++g) {
    int fi = g*256 + t;
    int r = fi >> 5, c4 = fi & 31;
    *(float4*)&xa[r*192 + c4*4] = *(const float4*)&x[(size_t)(row0+r)*CIN + c4*4];
  }
#pragma unroll
  for (int g = 0; g < 2; ++g) {
    int fi = g*256 + t;
    int r = fi >> 4, c4 = fi & 15;
    *(float4*)&xa[r*192 + 128 + c4*4] = *(const float4*)&agg[(size_t)(row0+r)*64 + c4*4];
  }
  __syncthreads();
  const int c4 = t & 31;
  const int rg = t >> 5;
  float acc[4][4];
#pragma unroll
  for (int r = 0; r < 4; ++r) { acc[r][0]=0.f; acc[r][1]=0.f; acc[r][2]=0.f; acc[r][3]=0.f; }
  for (int k = 0; k < 192; k += 4) {
    float4 w0 = *(const float4*)&wT[(size_t)(k+0)*COUT + c4*4];
    float4 w1 = *(const float4*)&wT[(size_t)(k+1)*COUT + c4*4];
    float4 w2 = *(const float4*)&wT[(size_t)(k+2)*COUT + c4*4];
    float4 w3 = *(const float4*)&wT[(size_t)(k+3)*COUT + c4*4];
#pragma unroll
    for (int r = 0; r < 4; ++r) {
      float4 xv = *(const float4*)&xa[(rg*4 + r)*192 + k];
      acc[r][0] = fmaf(xv.x, w0.x, fmaf(xv.y, w1.x, fmaf(xv.z, w2.x, fmaf(xv.w, w3.x, acc[r][0]))));
      acc[r][1] = fmaf(xv.x, w0.y, fmaf(xv.y, w1.y, fmaf(xv.z, w2.y, fmaf(xv.w, w3.y, acc[r][1]))));
      acc[r][2] = fmaf(xv.x, w0.z, fmaf(xv.y, w1.z, fmaf(xv.z, w2.z, fmaf(xv.w, w3.z, acc[r][2]))));
      acc[r][3] = fmaf(xv.x, w0.w, fmaf(xv.y, w1.w, fmaf(xv.z, w2.w, fmaf(xv.w, w3.w, acc[r][3]))));
    }
  }
  float4 bias = *(const float4*)&b2[c4*4];
#pragma unroll
  for (int r = 0; r < 4; ++r) {
    float4 o = make_float4(acc[r][0]+bias.x, acc[r][1]+bias.y, acc[r][2]+bias.z, acc[r][3]+bias.w);
    *(float4*)&out[(size_t)(row0 + rg*4 + r)*COUT + c4*4] = o;
  }
}

extern "C" void kernel_launch(void* const* d_in, const int* in_sizes, int n_in,
                              void* d_out, int out_size, void* d_ws, size_t ws_size,
                              hipStream_t stream) {
  const float* x  = (const float*)d_in[0];
  const float* Ws = (const float*)d_in[1];
  const float* bs = (const float*)d_in[2];
  const float* Wh = (const float*)d_in[3];
  const float* bh = (const float*)d_in[4];
  const float* W1 = (const float*)d_in[5];
  const float* W2 = (const float*)d_in[6];
  const float* b2 = (const float*)d_in[7];
  float* out = (float*)d_out;

  char* ws = (char*)d_ws;
  float4* s4 = (float4*)(ws + WS_S4);
  float*  h  = (float*) (ws + WS_H);

  k1_proj<<<NPTS/64, 256, 0, stream>>>(x, Ws, bs, Wh, bh, s4, h);

  if (ws_size >= (size_t)WS_NEED_M) {
    float* t2  = (float*)(ws + WS_T2);
    float* agg = (float*)(ws + WS_AGG_M);
    float* wT  = (float*)(ws + WS_WT_M);
    uint4* mw  = (uint4*)(ws + WS_MASK);
    k2t_thresh<<<NPTS/16, 256, 0, stream>>>(s4, t2);
    k2b_mask<<<2048, 256, 0, stream>>>(s4, t2, mw);
    k3_sel2<<<NPTS/QPB, 256, 0, stream>>>(s4, h, (const uint4*)mw, agg);
    k4a_wt<<<(192*COUT + 255)/256, 256, 0, stream>>>(W1, W2, wT);
    k4_out2<<<NPTS/32, 256, 0, stream>>>(x, agg, wT, b2, out);
  } else {
    unsigned short* cj = (unsigned short*)(ws + WS_CJ_F);
    float* agg = (float*)(ws + WS_AGG_F);
    float* wT  = (float*)(ws + WS_WT_F);
    k2_knn_fb<<<512, 256, 0, stream>>>(s4, cj);
    k3_merge_fb<<<NPTS/64, 256, 0, stream>>>(s4, (const float4*)h, cj, agg);
    k4a_wt<<<(192*COUT + 255)/256, 256, 0, stream>>>(W1, W2, wT);
    k4_out2<<<NPTS/32, 256, 0, stream>>>(x, agg, wT, b2, out);
  }
}